// Round 3
// baseline (612.325 us; speedup 1.0000x reference)
//
#include <hip/hip_runtime.h>
#include <stdint.h>

#define CD 128
#define LP 54
#define SW 136      // LDS row stride in bf16 elements
#define G  4        // batches per block
#define SCW 10      // sc row stride (floats)

using bfrag = __attribute__((ext_vector_type(8))) short;   // 8 bf16 = 4 VGPR
using f32x4 = __attribute__((ext_vector_type(4))) float;

__device__ __forceinline__ short f2bf(float x){
  union{float f; unsigned u;} v; v.f = x;
  unsigned r = (v.u + 0x7fffu + ((v.u >> 16) & 1u)) >> 16;
  return (short)r;
}
__device__ __forceinline__ float bf2f(short h){
  union{unsigned u; float f;} v; v.u = ((unsigned)(unsigned short)h) << 16;
  return v.f;
}
__device__ __forceinline__ unsigned pack2(float a, float b){
  return (unsigned)(unsigned short)f2bf(a) | ((unsigned)(unsigned short)f2bf(b) << 16);
}
__device__ __forceinline__ float gelu_exact(float z){
  return 0.5f * z * (1.0f + erff(z * 0.70710678118654752440f));
}
__device__ __forceinline__ int reg_of(int t){ return (t < 2) ? t : (t - 2); }

// ---------------- stage A (1 block): A[th][c] = 0.25*sum_d (LN(q)@Wq+bq)[t][h*16+d]*Wk[c][h*16+d]
// All weight MACs run from LDS (coalesced 64-row half staging). Af kept bf16.
// Output in MFMA B-fragment layout: slot (kt*4+nt)*64+lane, elem j =
// A[nt*16+(lane&15)][kt*32+(lane>>4)*8+j]
__global__ __launch_bounds__(256) void stageA(
  const float* __restrict__ query, const float* __restrict__ g1, const float* __restrict__ b1,
  const float* __restrict__ Wq, const float* __restrict__ bq, const float* __restrict__ Wk,
  short* __restrict__ Asw)
{
  __shared__ float qn[8][CD];        // 4 KB
  __shared__ float qq[8][CD];        // 4 KB
  __shared__ float Wt[64][129];      // 33 KB (reused: Wq halves then Wk halves)
  __shared__ short Afh[64][SW];      // 17 KB (bf16)
  const int tid = threadIdx.x;
  const int t = tid >> 5, lane = tid & 31;
  float xv[4]; float s = 0.f;
  for (int k = 0; k < 4; k++){ xv[k] = query[t*CD + lane + 32*k]; s += xv[k]; }
  for (int o = 16; o > 0; o >>= 1) s += __shfl_down(s, o, 32);
  const float m = __shfl(s, 0, 32) * (1.f/CD);
  float v = 0.f;
  for (int k = 0; k < 4; k++){ float d = xv[k] - m; v += d*d; }
  for (int o = 16; o > 0; o >>= 1) v += __shfl_down(v, o, 32);
  const float rstd = rsqrtf(__shfl(v, 0, 32) * (1.f/CD) + 1e-5f);
  for (int k = 0; k < 4; k++){
    int c = lane + 32*k;
    qn[t][c] = (xv[k] - m) * rstd * g1[c] + b1[c];
  }
  __syncthreads();

  // qq[t][j] = bq[j] + qn[t][:] @ Wq[:,j]  — two 64-row halves of Wq via LDS
  for (int half = 0; half < 2; half++){
    const float4* src = (const float4*)(Wq + (size_t)half*64*CD);
    #pragma unroll
    for (int k = 0; k < 8; k++){
      int idx = tid + k*256;           // 2048 float4 = 64 rows x 128 cols
      float4 w = src[idx];
      int row = idx >> 5, c4 = (idx & 31)*4;
      Wt[row][c4] = w.x; Wt[row][c4+1] = w.y; Wt[row][c4+2] = w.z; Wt[row][c4+3] = w.w;
    }
    __syncthreads();
    #pragma unroll
    for (int it = 0; it < 4; it++){
      int idx = tid + it*256;          // 1024 = 8 x 128 outputs
      int tt = idx >> 7, j = idx & 127;
      float acc = (half == 0) ? bq[j] : qq[tt][j];
      for (int c = 0; c < 64; c++) acc += qn[tt][half*64 + c] * Wt[c][j];
      qq[tt][j] = acc;
    }
    __syncthreads();
  }

  // Afh[t*8+h][c] = bf16( 0.25 * sum_d qq[t][h*16+d] * Wk[c][h*16+d] ) — halves over c (Wk rows)
  for (int half = 0; half < 2; half++){
    const float4* src = (const float4*)(Wk + (size_t)half*64*CD);
    #pragma unroll
    for (int k = 0; k < 8; k++){
      int idx = tid + k*256;
      float4 w = src[idx];
      int row = idx >> 5, c4 = (idx & 31)*4;
      Wt[row][c4] = w.x; Wt[row][c4+1] = w.y; Wt[row][c4+2] = w.z; Wt[row][c4+3] = w.w;
    }
    __syncthreads();
    #pragma unroll
    for (int k = 0; k < 16; k++){
      int o = k*256 + tid;             // 4096 = 64 th-rows x 64 cc
      int th = o >> 6, cc = o & 63;
      int tt = th >> 3, h = th & 7;
      float acc = 0.f;
      #pragma unroll
      for (int d = 0; d < 16; d++) acc += qq[tt][h*16 + d] * Wt[cc][h*16 + d];
      Afh[th][half*64 + cc] = f2bf(acc * 0.25f);  // scale (dim/heads)^-0.5 folded; q.bk dropped
    }
    __syncthreads();
  }

  for (int sfr = tid; sfr < 1024; sfr += 256){
    int ln = sfr & 63, nt = (sfr >> 6) & 3, kt = sfr >> 8;
    int l15 = ln & 15, qd = ln >> 4;
    bfrag r = *(const bfrag*)&Afh[nt*16 + l15][kt*32 + qd*8];
    ((bfrag*)Asw)[sfr] = r;   // slot == sfr by construction
  }
}

// ---------------- swizzle the 4 weight matrices into B-fragment layout (bf16) ----------------
// Coalesced global reads into LDS halves; strided reads hit LDS, not HBM.
__global__ __launch_bounds__(256) void swizzleW(
  const float* __restrict__ W0, const float* __restrict__ W1,
  const float* __restrict__ W2, const float* __restrict__ W3,
  short* __restrict__ dst)
{
  const float* W = (blockIdx.x == 0) ? W0 : (blockIdx.x == 1) ? W1 : (blockIdx.x == 2) ? W2 : W3;
  bfrag* out = (bfrag*)dst + (size_t)blockIdx.x * 2048;
  __shared__ float Wt[64][129];
  const int tid = threadIdx.x;
  for (int half = 0; half < 2; half++){
    const float4* src = (const float4*)(W + (size_t)half*64*CD);
    #pragma unroll
    for (int k = 0; k < 8; k++){
      int idx = tid + k*256;
      float4 w = src[idx];
      int row = idx >> 5, c4 = (idx & 31)*4;
      Wt[row][c4] = w.x; Wt[row][c4+1] = w.y; Wt[row][c4+2] = w.z; Wt[row][c4+3] = w.w;
    }
    __syncthreads();
    for (int s2 = tid; s2 < 1024; s2 += 256){
      int s = half*1024 + s2;          // kt = s>>9 in {2*half, 2*half+1}
      int ln = s & 63, nt = (s >> 6) & 7, kt = s >> 9;
      int l15 = ln & 15, qd = ln >> 4;
      bfrag r;
      #pragma unroll
      for (int j = 0; j < 8; j++) r[j] = f2bf(Wt[(kt & 1)*32 + qd*8 + j][nt*16 + l15]);
      out[s] = r;   // slot == s
    }
    __syncthreads();
  }
}

#define MFMA(a,b,c) __builtin_amdgcn_mfma_f32_16x16x32_bf16((a),(b),(c),0,0,0)

// GEMM helper, M=32: acc[4] += A_lds[32xCD bf16, stride SW] @ B-frags (wave: mh m-tile, nh n-half)
__device__ __forceinline__ void gemmC32(const short* __restrict__ Ab, const bfrag* __restrict__ BF,
                                        int mh, int nh, int l15, int qd, int lane, f32x4 acc[4]){
  #pragma unroll
  for (int kt = 0; kt < 4; kt++){
    bfrag a = *(const bfrag*)(Ab + (mh*16 + l15)*SW + kt*32 + qd*8);
    #pragma unroll
    for (int n4 = 0; n4 < 4; n4++){
      bfrag bF = BF[(kt*8 + nh*4 + n4)*64 + lane];
      acc[n4] = MFMA(a, bF, acc[n4]);
    }
  }
}

// ---------------- fused main kernel: G batches per block, ONE barrier per batch ----------------
// A-fragments loaded DIRECTLY from global tgt (no LDS staging, no staging barrier, no register
// prefetch array spill). vp/sc double-buffered so fold(g) can overlap writes(g+1).
// LDS arena 43200 B: vpA@0 (14688), vpB@14688 (14688), oall@29376 (8704), scA@38080 (2560),
// scB@40640 (2560). Phase C aliases: h2s=vpA, f1s=vpB, lnS/lnQ@scA, yst(f32 32x136)@0.
__global__ __launch_bounds__(256, 3) void fused(
  const float* __restrict__ query, const float* __restrict__ tgt,
  const float* __restrict__ g2, const float* __restrict__ b2,
  const float* __restrict__ bv, const float* __restrict__ bp,
  const float* __restrict__ bf1, const float* __restrict__ bf2,
  const short* __restrict__ Asw, const short* __restrict__ Wsw,
  float* __restrict__ outp)
{
  __shared__ __align__(16) unsigned char arena[43200];
  short* vpA  = (short*)arena;
  short* vpB  = (short*)(arena + 14688);
  short* oall = (short*)(arena + 29376);
  float* scA  = (float*)(arena + 38080);
  float* scB  = (float*)(arena + 40640);

  const int tid  = threadIdx.x;
  const int lane = tid & 63, wid = tid >> 6;
  const int mh = wid & 1, nh = wid >> 1;
  const int l15 = lane & 15, qd = lane >> 4;
  const int b0 = blockIdx.x * G;

  const bfrag* AF   = (const bfrag*)Asw;
  const bfrag* WvF  = (const bfrag*)Wsw;
  const bfrag* WpF  = (const bfrag*)Wsw + 2048;
  const bfrag* Wf1F = (const bfrag*)Wsw + 4096;
  const bfrag* Wf2F = (const bfrag*)Wsw + 6144;

  float bvv[4];
  #pragma unroll
  for (int n4 = 0; n4 < 4; n4++) bvv[n4] = bv[(nh*4 + n4)*16 + l15];

  // per-thread A-fragment source rows/cols (clamped: rows >= LP produce discarded outputs)
  int rr0, rr1;
  {
    int r0 = (mh*2 + 0)*16 + l15; rr0 = (r0 < LP) ? r0 : 0;
    int r1 = (mh*2 + 1)*16 + l15; rr1 = (r1 < LP) ? r1 : 0;
  }

  float4 ar[4][2][2];   // [kt][mt][half16B]
  // prologue: issue loads for batch 0
  {
    const float* bbase = tgt + (size_t)b0 * (LP*CD);
    #pragma unroll
    for (int kt = 0; kt < 4; kt++){
      const float4* p0 = (const float4*)(bbase + rr0*CD + kt*32 + qd*8);
      const float4* p1 = (const float4*)(bbase + rr1*CD + kt*32 + qd*8);
      ar[kt][0][0] = p0[0]; ar[kt][0][1] = p0[1];
      ar[kt][1][0] = p1[0]; ar[kt][1][1] = p1[1];
    }
  }

  for (int g = 0; g < G; g++){
    short* vp = (g & 1) ? vpB : vpA;
    float* sc = (g & 1) ? scB : scA;

    // convert arrived f32 fragments to bf16 MFMA A-frags
    bfrag af[4][2];
    #pragma unroll
    for (int kt = 0; kt < 4; kt++)
      #pragma unroll
      for (int mt = 0; mt < 2; mt++){
        float4 u = ar[kt][mt][0], w = ar[kt][mt][1];
        bfrag a;
        a[0] = f2bf(u.x); a[1] = f2bf(u.y); a[2] = f2bf(u.z); a[3] = f2bf(u.w);
        a[4] = f2bf(w.x); a[5] = f2bf(w.y); a[6] = f2bf(w.z); a[7] = f2bf(w.w);
        af[kt][mt] = a;
      }

    // scores (N=64) + vproj (N=128) MFMA; B-frags streamed from L1/L2
    f32x4 sacc[2][2];
    f32x4 vacc[2][4];
    #pragma unroll
    for (int mt = 0; mt < 2; mt++){
      #pragma unroll
      for (int n2 = 0; n2 < 2; n2++) sacc[mt][n2] = (f32x4){0.f, 0.f, 0.f, 0.f};
      #pragma unroll
      for (int n4 = 0; n4 < 4; n4++) vacc[mt][n4] = (f32x4){bvv[n4], bvv[n4], bvv[n4], bvv[n4]};
    }
    #pragma unroll
    for (int kt = 0; kt < 4; kt++){
      bfrag s0 = AF[(kt*4 + nh*2 + 0)*64 + lane];
      bfrag s1 = AF[(kt*4 + nh*2 + 1)*64 + lane];
      bfrag w0 = WvF[(kt*8 + nh*4 + 0)*64 + lane];
      bfrag w1 = WvF[(kt*8 + nh*4 + 1)*64 + lane];
      bfrag w2 = WvF[(kt*8 + nh*4 + 2)*64 + lane];
      bfrag w3 = WvF[(kt*8 + nh*4 + 3)*64 + lane];
      #pragma unroll
      for (int mt = 0; mt < 2; mt++){
        sacc[mt][0] = MFMA(af[kt][mt], s0, sacc[mt][0]);
        sacc[mt][1] = MFMA(af[kt][mt], s1, sacc[mt][1]);
        vacc[mt][0] = MFMA(af[kt][mt], w0, vacc[mt][0]);
        vacc[mt][1] = MFMA(af[kt][mt], w1, vacc[mt][1]);
        vacc[mt][2] = MFMA(af[kt][mt], w2, vacc[mt][2]);
        vacc[mt][3] = MFMA(af[kt][mt], w3, vacc[mt][3]);
      }
    }

    // store scores (region-filtered -> sc[th][ll], raw) and vproj (bf16, guarded to 54 rows)
    #pragma unroll
    for (int mt = 0; mt < 2; mt++){
      #pragma unroll
      for (int reg = 0; reg < 4; reg++){
        int l = (mh*2 + mt)*16 + qd*4 + reg;
        if (l < LP){
          int hr = l / 9, wc = l - hr*9;
          int hq = hr / 3, wq = wc / 3;
          int rl = hq*3 + wq;
          int ll = (hr - hq*3)*3 + (wc - wq*3);
          #pragma unroll
          for (int n2 = 0; n2 < 2; n2++){
            int th = (nh*2 + n2)*16 + l15;
            int t  = th >> 3;
            int rt = reg_of(t);
            if (rl == rt) sc[th*SCW + ll] = sacc[mt][n2][reg];
          }
          #pragma unroll
          for (int n4 = 0; n4 < 4; n4++){
            int col = (nh*4 + n4)*16 + l15;
            vp[l*SW + col] = f2bf(vacc[mt][n4][reg]);
          }
        }
      }
    }

    // issue loads for batch g+1 (accumulators dead; latency hides under barrier + fold)
    if (g + 1 < G){
      const float* bbase = tgt + (size_t)(b0 + g + 1) * (LP*CD);
      #pragma unroll
      for (int kt = 0; kt < 4; kt++){
        const float4* p0 = (const float4*)(bbase + rr0*CD + kt*32 + qd*8);
        const float4* p1 = (const float4*)(bbase + rr1*CD + kt*32 + qd*8);
        ar[kt][0][0] = p0[0]; ar[kt][0][1] = p0[1];
        ar[kt][1][0] = p1[0]; ar[kt][1][1] = p1[1];
      }
    }

    __syncthreads();   // vp + sc visible

    // fold with inline softmax: thread (wid,l15,qd) -> row th=wid*16+l15, cols h*16+qd*4..+3
    {
      const int th = wid*16 + l15;
      const int t  = th >> 3, h = th & 7;
      const int rt = reg_of(t);
      const int rh = (rt >= 3) ? 1 : 0;
      const int pbase = rh*27 + (rt - rh*3)*3;
      const float* p = sc + th*SCW;
      float mx = p[0];
      #pragma unroll
      for (int i = 1; i < 9; i++) mx = fmaxf(mx, p[i]);
      float w[9]; float su = 0.f;
      #pragma unroll
      for (int i = 0; i < 9; i++){ float e = __expf(p[i] - mx); w[i] = e; su += e; }
      const float inv = 1.f / su;
      const int cbase = h*16 + qd*4;
      float a0 = 0.f, a1 = 0.f, a2 = 0.f, a3 = 0.f;
      #pragma unroll
      for (int ll = 0; ll < 9; ll++){
        const int pos = pbase + (ll/3)*9 + (ll%3);
        uint2 pv = *(const uint2*)(vp + pos*SW + cbase);
        float wl = w[ll];
        a0 += wl * bf2f((short)(pv.x & 0xffff));
        a1 += wl * bf2f((short)(pv.x >> 16));
        a2 += wl * bf2f((short)(pv.y & 0xffff));
        a3 += wl * bf2f((short)(pv.y >> 16));
      }
      uint2 ov; ov.x = pack2(a0*inv, a1*inv); ov.y = pack2(a2*inv, a3*inv);
      *(uint2*)(oall + (g*8 + t)*SW + cbase) = ov;
    }
    // no trailing barrier: next iteration writes the OTHER vp/sc buffer;
    // re-use of THIS buffer (g+2) is ordered by the next iteration's barrier.
  }
  __syncthreads();   // oall complete

  // ================= phase C: rows m = g*8+t (M=32) =================
  // x = query_row + oall @ Wp + bp    (x kept f32 in registers)
  f32x4 xacc[4];
  #pragma unroll
  for (int n4 = 0; n4 < 4; n4++){
    int col = (nh*4 + n4)*16 + l15;
    float bpv = bp[col];
    #pragma unroll
    for (int reg = 0; reg < 4; reg++){
      int t = (qd*4 + reg) & 7;
      xacc[n4][reg] = bpv + query[t*CD + col];
    }
  }
  gemmC32(oall, WpF, mh, nh, l15, qd, lane, xacc);

  // LayerNorm over rows (cross-wave partials via LDS)
  float* lnS = scA;         // [32][2]
  float* lnQ = scA + 64;    // [32][2]
  #pragma unroll
  for (int reg = 0; reg < 4; reg++){
    float x0 = xacc[0][reg], x1 = xacc[1][reg], x2 = xacc[2][reg], x3 = xacc[3][reg];
    float pp = x0 + x1 + x2 + x3;
    float p2 = x0*x0 + x1*x1 + x2*x2 + x3*x3;
    #pragma unroll
    for (int msk = 1; msk < 16; msk <<= 1){
      pp += __shfl_xor(pp, msk);
      p2 += __shfl_xor(p2, msk);
    }
    if (l15 == 0){
      int row = mh*16 + qd*4 + reg;
      lnS[row*2 + nh] = pp;
      lnQ[row*2 + nh] = p2;
    }
  }
  __syncthreads();
  short* h2s = vpA;
  {
    float g2v[4], b2v[4];
    #pragma unroll
    for (int n4 = 0; n4 < 4; n4++){
      int col = (nh*4 + n4)*16 + l15;
      g2v[n4] = g2[col]; b2v[n4] = b2[col];
    }
    #pragma unroll
    for (int reg = 0; reg < 4; reg++){
      int row = mh*16 + qd*4 + reg;
      float su = lnS[row*2] + lnS[row*2 + 1];
      float sq = lnQ[row*2] + lnQ[row*2 + 1];
      float mu = su * (1.f/CD);
      float var = sq * (1.f/CD) - mu*mu;
      float rs = rsqrtf(var + 1e-5f);
      #pragma unroll
      for (int n4 = 0; n4 < 4; n4++){
        int col = (nh*4 + n4)*16 + l15;
        h2s[row*SW + col] = f2bf((xacc[n4][reg] - mu) * rs * g2v[n4] + b2v[n4]);
      }
    }
  }
  __syncthreads();

  // f1 = gelu(h2 @ Wf1 + bf1)
  short* f1s = vpB;
  f32x4 facc[4];
  #pragma unroll
  for (int n4 = 0; n4 < 4; n4++){
    int col = (nh*4 + n4)*16 + l15;
    float bv1 = bf1[col];
    #pragma unroll
    for (int reg = 0; reg < 4; reg++) facc[n4][reg] = bv1;
  }
  gemmC32(h2s, Wf1F, mh, nh, l15, qd, lane, facc);
  #pragma unroll
  for (int reg = 0; reg < 4; reg++){
    int row = mh*16 + qd*4 + reg;
    #pragma unroll
    for (int n4 = 0; n4 < 4; n4++){
      int col = (nh*4 + n4)*16 + l15;
      f1s[row*SW + col] = f2bf(gelu_exact(facc[n4][reg]));
    }
  }
  __syncthreads();

  // y = x + f1 @ Wf2 + bf2
  f32x4 yacc[4];
  #pragma unroll
  for (int n4 = 0; n4 < 4; n4++){
    int col = (nh*4 + n4)*16 + l15;
    float bv2 = bf2[col];
    #pragma unroll
    for (int reg = 0; reg < 4; reg++) yacc[n4][reg] = bv2;
  }
  gemmC32(f1s, Wf2F, mh, nh, l15, qd, lane, yacc);
  __syncthreads();   // all f1s reads done before yst (aliases vpA+vpB head) is written

  // stage y in LDS f32 (conflict-free stride 136), then coalesced float4 store
  float* yst = (float*)arena;   // [32][136] f32
  #pragma unroll
  for (int reg = 0; reg < 4; reg++){
    int row = mh*16 + qd*4 + reg;
    #pragma unroll
    for (int n4 = 0; n4 < 4; n4++){
      int col = (nh*4 + n4)*16 + l15;
      yst[row*136 + col] = xacc[n4][reg] + yacc[n4][reg];
    }
  }
  __syncthreads();
  {
    const size_t obase = (size_t)blockIdx.x * (G*8*CD);
    float4* dst = (float4*)(outp + obase);
    #pragma unroll
    for (int k2 = 0; k2 < 4; k2++){
      int idx = tid + k2*256;
      int row = idx >> 5, c4 = idx & 31;
      dst[idx] = *(const float4*)(yst + row*136 + c4*4);
    }
  }
}

extern "C" void kernel_launch(void* const* d_in, const int* in_sizes, int n_in,
                              void* d_out, int out_size, void* d_ws, size_t ws_size,
                              hipStream_t stream)
{
  const int B = in_sizes[1] / (LP*CD);   // 8192
  short* Asw = (short*)d_ws;                              // 16 KB
  short* Wsw = (short*)((char*)d_ws + 16384);             // 4 x 32 KB

  stageA<<<1, 256, 0, stream>>>(
      (const float*)d_in[0], (const float*)d_in[2], (const float*)d_in[3],
      (const float*)d_in[6], (const float*)d_in[7], (const float*)d_in[8], Asw);

  swizzleW<<<4, 256, 0, stream>>>(
      (const float*)d_in[10], (const float*)d_in[12],
      (const float*)d_in[14], (const float*)d_in[16], Wsw);

  fused<<<B / G, 256, 0, stream>>>(
      (const float*)d_in[0], (const float*)d_in[1],
      (const float*)d_in[4], (const float*)d_in[5],
      (const float*)d_in[11], (const float*)d_in[13],
      (const float*)d_in[15], (const float*)d_in[17],
      Asw, Wsw, (float*)d_out);
}

// Round 4
// 426.307 us; speedup vs baseline: 1.4363x; 1.4363x over previous
//
#include <hip/hip_runtime.h>
#include <stdint.h>

#define CD 128
#define LP 54
#define SW 136      // LDS row stride in bf16 elements
#define G  8        // batches per block
#define SCW 10      // sc row stride (floats)

using bfrag = __attribute__((ext_vector_type(8))) short;   // 8 bf16 = 4 VGPR
using f32x4 = __attribute__((ext_vector_type(4))) float;

__device__ __forceinline__ short f2bf(float x){
  union{float f; unsigned u;} v; v.f = x;
  unsigned r = (v.u + 0x7fffu + ((v.u >> 16) & 1u)) >> 16;
  return (short)r;
}
__device__ __forceinline__ float bf2f(short h){
  union{unsigned u; float f;} v; v.u = ((unsigned)(unsigned short)h) << 16;
  return v.f;
}
__device__ __forceinline__ unsigned pack2(float a, float b){
  return (unsigned)(unsigned short)f2bf(a) | ((unsigned)(unsigned short)f2bf(b) << 16);
}
__device__ __forceinline__ float gelu_exact(float z){
  return 0.5f * z * (1.0f + erff(z * 0.70710678118654752440f));
}
__device__ __forceinline__ int reg_of(int t){ return (t < 2) ? t : (t - 2); }

// ---------------- stage A (1 block): A[th][c] = 0.25*sum_d (LN(q)@Wq+bq)[t][h*16+d]*Wk[c][h*16+d]
// All weight MACs run from LDS (coalesced 64-row half staging). Af kept bf16.
// Output in MFMA B-fragment layout: slot (kt*4+nt)*64+lane, elem j =
// A[nt*16+(lane&15)][kt*32+(lane>>4)*8+j]
__global__ __launch_bounds__(256) void stageA(
  const float* __restrict__ query, const float* __restrict__ g1, const float* __restrict__ b1,
  const float* __restrict__ Wq, const float* __restrict__ bq, const float* __restrict__ Wk,
  short* __restrict__ Asw)
{
  __shared__ float qn[8][CD];        // 4 KB
  __shared__ float qq[8][CD];        // 4 KB
  __shared__ float Wt[64][129];      // 33 KB (reused: Wq halves then Wk halves)
  __shared__ short Afh[64][SW];      // 17 KB (bf16)
  const int tid = threadIdx.x;
  const int t = tid >> 5, lane = tid & 31;
  float xv[4]; float s = 0.f;
  for (int k = 0; k < 4; k++){ xv[k] = query[t*CD + lane + 32*k]; s += xv[k]; }
  for (int o = 16; o > 0; o >>= 1) s += __shfl_down(s, o, 32);
  const float m = __shfl(s, 0, 32) * (1.f/CD);
  float v = 0.f;
  for (int k = 0; k < 4; k++){ float d = xv[k] - m; v += d*d; }
  for (int o = 16; o > 0; o >>= 1) v += __shfl_down(v, o, 32);
  const float rstd = rsqrtf(__shfl(v, 0, 32) * (1.f/CD) + 1e-5f);
  for (int k = 0; k < 4; k++){
    int c = lane + 32*k;
    qn[t][c] = (xv[k] - m) * rstd * g1[c] + b1[c];
  }
  __syncthreads();

  // qq[t][j] = bq[j] + qn[t][:] @ Wq[:,j]  — two 64-row halves of Wq via LDS
  for (int half = 0; half < 2; half++){
    const float4* src = (const float4*)(Wq + (size_t)half*64*CD);
    #pragma unroll
    for (int k = 0; k < 8; k++){
      int idx = tid + k*256;           // 2048 float4 = 64 rows x 128 cols
      float4 w = src[idx];
      int row = idx >> 5, c4 = (idx & 31)*4;
      Wt[row][c4] = w.x; Wt[row][c4+1] = w.y; Wt[row][c4+2] = w.z; Wt[row][c4+3] = w.w;
    }
    __syncthreads();
    #pragma unroll
    for (int it = 0; it < 4; it++){
      int idx = tid + it*256;          // 1024 = 8 x 128 outputs
      int tt = idx >> 7, j = idx & 127;
      float acc = (half == 0) ? bq[j] : qq[tt][j];
      for (int c = 0; c < 64; c++) acc += qn[tt][half*64 + c] * Wt[c][j];
      qq[tt][j] = acc;
    }
    __syncthreads();
  }

  // Afh[t*8+h][c] = bf16( 0.25 * sum_d qq[t][h*16+d] * Wk[c][h*16+d] ) — halves over c (Wk rows)
  for (int half = 0; half < 2; half++){
    const float4* src = (const float4*)(Wk + (size_t)half*64*CD);
    #pragma unroll
    for (int k = 0; k < 8; k++){
      int idx = tid + k*256;
      float4 w = src[idx];
      int row = idx >> 5, c4 = (idx & 31)*4;
      Wt[row][c4] = w.x; Wt[row][c4+1] = w.y; Wt[row][c4+2] = w.z; Wt[row][c4+3] = w.w;
    }
    __syncthreads();
    #pragma unroll
    for (int k = 0; k < 16; k++){
      int o = k*256 + tid;             // 4096 = 64 th-rows x 64 cc
      int th = o >> 6, cc = o & 63;
      int tt = th >> 3, h = th & 7;
      float acc = 0.f;
      #pragma unroll
      for (int d = 0; d < 16; d++) acc += qq[tt][h*16 + d] * Wt[cc][h*16 + d];
      Afh[th][half*64 + cc] = f2bf(acc * 0.25f);  // scale (dim/heads)^-0.5 folded; q.bk dropped
    }
    __syncthreads();
  }

  for (int sfr = tid; sfr < 1024; sfr += 256){
    int ln = sfr & 63, nt = (sfr >> 6) & 3, kt = sfr >> 8;
    int l15 = ln & 15, qd = ln >> 4;
    bfrag r = *(const bfrag*)&Afh[nt*16 + l15][kt*32 + qd*8];
    ((bfrag*)Asw)[sfr] = r;   // slot == sfr by construction
  }
}

// ---------------- swizzle the 4 weight matrices into B-fragment layout (bf16) ----------------
// Coalesced global reads into LDS halves; strided reads hit LDS, not HBM.
__global__ __launch_bounds__(256) void swizzleW(
  const float* __restrict__ W0, const float* __restrict__ W1,
  const float* __restrict__ W2, const float* __restrict__ W3,
  short* __restrict__ dst)
{
  const float* W = (blockIdx.x == 0) ? W0 : (blockIdx.x == 1) ? W1 : (blockIdx.x == 2) ? W2 : W3;
  bfrag* out = (bfrag*)dst + (size_t)blockIdx.x * 2048;
  __shared__ float Wt[64][129];
  const int tid = threadIdx.x;
  for (int half = 0; half < 2; half++){
    const float4* src = (const float4*)(W + (size_t)half*64*CD);
    #pragma unroll
    for (int k = 0; k < 8; k++){
      int idx = tid + k*256;
      float4 w = src[idx];
      int row = idx >> 5, c4 = (idx & 31)*4;
      Wt[row][c4] = w.x; Wt[row][c4+1] = w.y; Wt[row][c4+2] = w.z; Wt[row][c4+3] = w.w;
    }
    __syncthreads();
    for (int s2 = tid; s2 < 1024; s2 += 256){
      int s = half*1024 + s2;          // kt = s>>9 in {2*half, 2*half+1}
      int ln = s & 63, nt = (s >> 6) & 7, kt = s >> 9;
      int l15 = ln & 15, qd = ln >> 4;
      bfrag r;
      #pragma unroll
      for (int j = 0; j < 8; j++) r[j] = f2bf(Wt[(kt & 1)*32 + qd*8 + j][nt*16 + l15]);
      out[s] = r;   // slot == s
    }
    __syncthreads();
  }
}

#define MFMA(a,b,c) __builtin_amdgcn_mfma_f32_16x16x32_bf16((a),(b),(c),0,0,0)

// GEMM helper, M=64: acc[2][4] += A_lds[64xCD bf16, stride SW] @ B-frags (wave: mh m-half, nh n-half)
__device__ __forceinline__ void gemmC(const short* __restrict__ Ab, const bfrag* __restrict__ BF,
                                      int mh, int nh, int l15, int qd, int lane, f32x4 acc[2][4]){
  #pragma unroll
  for (int kt = 0; kt < 4; kt++){
    bfrag a0 = *(const bfrag*)(Ab + ((mh*2+0)*16 + l15)*SW + kt*32 + qd*8);
    bfrag a1 = *(const bfrag*)(Ab + ((mh*2+1)*16 + l15)*SW + kt*32 + qd*8);
    #pragma unroll
    for (int n4 = 0; n4 < 4; n4++){
      bfrag bF = BF[(kt*8 + nh*4 + n4)*64 + lane];
      acc[0][n4] = MFMA(a0, bF, acc[0][n4]);
      acc[1][n4] = MFMA(a1, bF, acc[1][n4]);
    }
  }
}

// ---------------- fused main kernel: G batches per block, ONE barrier per batch ----------------
// Wave w owns M-tile w (tgt rows w*16..w*16+15) and computes ALL N (scores N=64, vproj N=128):
// each tgt element read from global exactly ONCE per block (no nh duplication).
// B-fragments (Asw 16KB + Wv 32KB) streamed from L1/L2 (same addresses in all waves).
// LDS arena 51904 B: vpA@0 (14688), vpB@14688 (14688), oall@29376 (64x136 bf16 = 17408),
// scA@46784 (2560), scB@49344 (2560).
// Phase C aliases: h2s@0 (17408), f1s@17408 (17408, overlaps dead oall head), lnS/lnQ@scA,
// yst(f32 64x136 = 34816)@0.
__global__ __launch_bounds__(256, 1) void fused(
  const float* __restrict__ query, const float* __restrict__ tgt,
  const float* __restrict__ g2, const float* __restrict__ b2,
  const float* __restrict__ bv, const float* __restrict__ bp,
  const float* __restrict__ bf1, const float* __restrict__ bf2,
  const short* __restrict__ Asw, const short* __restrict__ Wsw,
  float* __restrict__ outp)
{
  __shared__ __align__(16) unsigned char arena[51904];
  short* vpA  = (short*)arena;
  short* vpB  = (short*)(arena + 14688);
  short* oall = (short*)(arena + 29376);
  float* scA  = (float*)(arena + 46784);
  float* scB  = (float*)(arena + 49344);

  const int tid  = threadIdx.x;
  const int lane = tid & 63, wid = tid >> 6;
  const int l15 = lane & 15, qd = lane >> 4;
  const int b0 = blockIdx.x * G;

  const bfrag* AF   = (const bfrag*)Asw;
  const bfrag* WvF  = (const bfrag*)Wsw;
  const bfrag* WpF  = (const bfrag*)Wsw + 2048;
  const bfrag* Wf1F = (const bfrag*)Wsw + 4096;
  const bfrag* Wf2F = (const bfrag*)Wsw + 6144;

  float bvv[8];
  #pragma unroll
  for (int nt = 0; nt < 8; nt++) bvv[nt] = bv[nt*16 + l15];

  // this wave's tgt row (one row per lane; clamp rows >= LP -> 0, outputs discarded)
  int rr = wid*16 + l15;
  if (rr >= LP) rr = 0;

  float4 ar[4][2];   // [kt][2 x float4] — 32 VGPRs of prefetch state
  {
    const float* bbase = tgt + (size_t)b0 * (LP*CD) + rr*CD;
    #pragma unroll
    for (int kt = 0; kt < 4; kt++){
      const float4* p = (const float4*)(bbase + kt*32 + qd*8);
      ar[kt][0] = p[0]; ar[kt][1] = p[1];
    }
  }

  for (int g = 0; g < G; g++){
    short* vp = (g & 1) ? vpB : vpA;
    float* sc = (g & 1) ? scB : scA;

    // convert arrived f32 fragments to bf16 MFMA A-frags (ar dies here)
    bfrag af[4];
    #pragma unroll
    for (int kt = 0; kt < 4; kt++){
      float4 u = ar[kt][0], w = ar[kt][1];
      bfrag a;
      a[0] = f2bf(u.x); a[1] = f2bf(u.y); a[2] = f2bf(u.z); a[3] = f2bf(u.w);
      a[4] = f2bf(w.x); a[5] = f2bf(w.y); a[6] = f2bf(w.z); a[7] = f2bf(w.w);
      af[kt] = a;
    }

    // scores (N=64, nt 0..3) + vproj (N=128, nt 0..7); B-frags streamed from L1/L2
    f32x4 sacc[4];
    f32x4 vacc[8];
    #pragma unroll
    for (int nt = 0; nt < 4; nt++) sacc[nt] = (f32x4){0.f, 0.f, 0.f, 0.f};
    #pragma unroll
    for (int nt = 0; nt < 8; nt++) vacc[nt] = (f32x4){bvv[nt], bvv[nt], bvv[nt], bvv[nt]};
    #pragma unroll
    for (int kt = 0; kt < 4; kt++){
      bfrag a = af[kt];
      #pragma unroll
      for (int nt = 0; nt < 4; nt++)
        sacc[nt] = MFMA(a, AF[(kt*4 + nt)*64 + lane], sacc[nt]);
      #pragma unroll
      for (int nt = 0; nt < 8; nt++)
        vacc[nt] = MFMA(a, WvF[(kt*8 + nt)*64 + lane], vacc[nt]);
    }

    // store scores (region-filtered -> sc[th][ll], raw) and vproj (bf16), rows guarded to 54
    #pragma unroll
    for (int reg = 0; reg < 4; reg++){
      int l = wid*16 + qd*4 + reg;
      if (l < LP){
        int hr = l / 9, wc = l - hr*9;
        int hq = hr / 3, wq = wc / 3;
        int rl = hq*3 + wq;
        int ll = (hr - hq*3)*3 + (wc - wq*3);
        #pragma unroll
        for (int nt = 0; nt < 4; nt++){
          int th = nt*16 + l15;
          int rt = reg_of(th >> 3);
          if (rl == rt) sc[th*SCW + ll] = sacc[nt][reg];
        }
        #pragma unroll
        for (int nt = 0; nt < 8; nt++){
          int col = nt*16 + l15;
          vp[l*SW + col] = f2bf(vacc[nt][reg]);
        }
      }
    }

    // issue prefetch for batch g+1 (latency hides under barrier + fold)
    if (g + 1 < G){
      const float* bbase = tgt + (size_t)(b0 + g + 1) * (LP*CD) + rr*CD;
      #pragma unroll
      for (int kt = 0; kt < 4; kt++){
        const float4* p = (const float4*)(bbase + kt*32 + qd*8);
        ar[kt][0] = p[0]; ar[kt][1] = p[1];
      }
    }

    __syncthreads();   // vp + sc visible

    // fold with inline softmax: thread (wid,l15,qd) -> row th=wid*16+l15, cols h*16+qd*4..+3
    {
      const int th = wid*16 + l15;
      const int t  = th >> 3, h = th & 7;
      const int rt = reg_of(t);
      const int rh = (rt >= 3) ? 1 : 0;
      const int pbase = rh*27 + (rt - rh*3)*3;
      const float* p = sc + th*SCW;
      float mx = p[0];
      #pragma unroll
      for (int i = 1; i < 9; i++) mx = fmaxf(mx, p[i]);
      float w[9]; float su = 0.f;
      #pragma unroll
      for (int i = 0; i < 9; i++){ float e = __expf(p[i] - mx); w[i] = e; su += e; }
      const float inv = 1.f / su;
      const int cbase = h*16 + qd*4;
      float a0 = 0.f, a1 = 0.f, a2 = 0.f, a3 = 0.f;
      #pragma unroll
      for (int ll = 0; ll < 9; ll++){
        const int pos = pbase + (ll/3)*9 + (ll%3);
        uint2 pv = *(const uint2*)(vp + pos*SW + cbase);
        float wl = w[ll];
        a0 += wl * bf2f((short)(pv.x & 0xffff));
        a1 += wl * bf2f((short)(pv.x >> 16));
        a2 += wl * bf2f((short)(pv.y & 0xffff));
        a3 += wl * bf2f((short)(pv.y >> 16));
      }
      uint2 ov; ov.x = pack2(a0*inv, a1*inv); ov.y = pack2(a2*inv, a3*inv);
      *(uint2*)(oall + (g*8 + t)*SW + cbase) = ov;
    }
    // no trailing barrier: next iter writes the OTHER vp/sc buffer; buffer re-use at g+2
    // is ordered by the (g+1) barrier.
  }
  __syncthreads();   // oall complete

  // ================= phase C: rows m = g*8+t (M=64) =================
  const int mh = wid & 1, nh = wid >> 1;

  // x = query_row + oall @ Wp + bp    (x kept f32 in registers)
  f32x4 xacc[2][4];
  #pragma unroll
  for (int n4 = 0; n4 < 4; n4++){
    int col = (nh*4 + n4)*16 + l15;
    float bpv = bp[col];
    #pragma unroll
    for (int reg = 0; reg < 4; reg++){
      int t = (qd*4 + reg) & 7;
      float val = bpv + query[t*CD + col];
      xacc[0][n4][reg] = val;
      xacc[1][n4][reg] = val;
    }
  }
  gemmC(oall, WpF, mh, nh, l15, qd, lane, xacc);

  // LayerNorm over rows (cross-wave partials via LDS)
  float* lnS = scA;          // [64][2]
  float* lnQ = scA + 128;    // [64][2]
  #pragma unroll
  for (int mt = 0; mt < 2; mt++){
    #pragma unroll
    for (int reg = 0; reg < 4; reg++){
      float x0 = xacc[mt][0][reg], x1 = xacc[mt][1][reg], x2 = xacc[mt][2][reg], x3 = xacc[mt][3][reg];
      float pp = x0 + x1 + x2 + x3;
      float p2 = x0*x0 + x1*x1 + x2*x2 + x3*x3;
      #pragma unroll
      for (int msk = 1; msk < 16; msk <<= 1){
        pp += __shfl_xor(pp, msk);
        p2 += __shfl_xor(p2, msk);
      }
      if (l15 == 0){
        int row = (mh*2 + mt)*16 + qd*4 + reg;
        lnS[row*2 + nh] = pp;
        lnQ[row*2 + nh] = p2;
      }
    }
  }
  __syncthreads();
  short* h2s = (short*)arena;            // 64 x SW bf16 (17408 B)
  {
    float g2v[4], b2v[4];
    #pragma unroll
    for (int n4 = 0; n4 < 4; n4++){
      int col = (nh*4 + n4)*16 + l15;
      g2v[n4] = g2[col]; b2v[n4] = b2[col];
    }
    #pragma unroll
    for (int mt = 0; mt < 2; mt++){
      #pragma unroll
      for (int reg = 0; reg < 4; reg++){
        int row = (mh*2 + mt)*16 + qd*4 + reg;
        float su = lnS[row*2] + lnS[row*2 + 1];
        float sq = lnQ[row*2] + lnQ[row*2 + 1];
        float mu = su * (1.f/CD);
        float var = sq * (1.f/CD) - mu*mu;
        float rs = rsqrtf(var + 1e-5f);
        #pragma unroll
        for (int n4 = 0; n4 < 4; n4++){
          int col = (nh*4 + n4)*16 + l15;
          h2s[row*SW + col] = f2bf((xacc[mt][n4][reg] - mu) * rs * g2v[n4] + b2v[n4]);
        }
      }
    }
  }
  __syncthreads();

  // f1 = gelu(h2 @ Wf1 + bf1)
  short* f1s = (short*)(arena + 17408);  // 64 x SW bf16 (overlaps dead oall head)
  f32x4 facc[2][4];
  #pragma unroll
  for (int n4 = 0; n4 < 4; n4++){
    int col = (nh*4 + n4)*16 + l15;
    float bv1 = bf1[col];
    #pragma unroll
    for (int reg = 0; reg < 4; reg++){ facc[0][n4][reg] = bv1; facc[1][n4][reg] = bv1; }
  }
  gemmC(h2s, Wf1F, mh, nh, l15, qd, lane, facc);
  #pragma unroll
  for (int mt = 0; mt < 2; mt++)
    #pragma unroll
    for (int reg = 0; reg < 4; reg++){
      int row = (mh*2 + mt)*16 + qd*4 + reg;
      #pragma unroll
      for (int n4 = 0; n4 < 4; n4++){
        int col = (nh*4 + n4)*16 + l15;
        f1s[row*SW + col] = f2bf(gelu_exact(facc[mt][n4][reg]));
      }
    }
  __syncthreads();

  // y = x + f1 @ Wf2 + bf2
  f32x4 yacc[2][4];
  #pragma unroll
  for (int n4 = 0; n4 < 4; n4++){
    int col = (nh*4 + n4)*16 + l15;
    float bv2 = bf2[col];
    #pragma unroll
    for (int reg = 0; reg < 4; reg++){ yacc[0][n4][reg] = bv2; yacc[1][n4][reg] = bv2; }
  }
  gemmC(f1s, Wf2F, mh, nh, l15, qd, lane, yacc);
  __syncthreads();   // all f1s reads done before yst (aliases h2s+f1s) is written

  // stage y in LDS f32 (stride 136), then coalesced float4 store
  float* yst = (float*)arena;   // [64][136] f32 = 34816 B
  #pragma unroll
  for (int mt = 0; mt < 2; mt++)
    #pragma unroll
    for (int reg = 0; reg < 4; reg++){
      int row = (mh*2 + mt)*16 + qd*4 + reg;
      #pragma unroll
      for (int n4 = 0; n4 < 4; n4++){
        int col = (nh*4 + n4)*16 + l15;
        yst[row*136 + col] = xacc[mt][n4][reg] + yacc[mt][n4][reg];
      }
    }
  __syncthreads();
  {
    const size_t obase = (size_t)blockIdx.x * (G*8*CD);
    float4* dst = (float4*)(outp + obase);
    #pragma unroll
    for (int k2 = 0; k2 < 8; k2++){
      int idx = tid + k2*256;
      int row = idx >> 5, c4 = idx & 31;
      dst[idx] = *(const float4*)(yst + row*136 + c4*4);
    }
  }
}

extern "C" void kernel_launch(void* const* d_in, const int* in_sizes, int n_in,
                              void* d_out, int out_size, void* d_ws, size_t ws_size,
                              hipStream_t stream)
{
  const int B = in_sizes[1] / (LP*CD);   // 8192
  short* Asw = (short*)d_ws;                              // 16 KB
  short* Wsw = (short*)((char*)d_ws + 16384);             // 4 x 32 KB

  stageA<<<1, 256, 0, stream>>>(
      (const float*)d_in[0], (const float*)d_in[2], (const float*)d_in[3],
      (const float*)d_in[6], (const float*)d_in[7], (const float*)d_in[8], Asw);

  swizzleW<<<4, 256, 0, stream>>>(
      (const float*)d_in[10], (const float*)d_in[12],
      (const float*)d_in[14], (const float*)d_in[16], Wsw);

  fused<<<B / G, 256, 0, stream>>>(
      (const float*)d_in[0], (const float*)d_in[1],
      (const float*)d_in[4], (const float*)d_in[5],
      (const float*)d_in[11], (const float*)d_in[13],
      (const float*)d_in[15], (const float*)d_in[17],
      Asw, Wsw, (float*)d_out);
}